// Round 5
// baseline (960.902 us; speedup 1.0000x reference)
//
#include <hip/hip_runtime.h>
#include <hip/hip_bf16.h>

// SwinMLP block, fp32 in/out, bf16 MFMA internals.
// Pipeline:
//   1) cvt_t: w1 -> w1t (bf16, N x K), w2 -> w2t (bf16, N x K)
//   2) fused_pre: LN1 + per-head 32x32 spatial matmul + residual -> x2 (fp32, d_out)
//      + LN2(x2) -> y (bf16, ws)
//   3) gemm4p<512,2048,GELU>: z = gelu(y @ w1 + b1)  (bf16, ws)
//   4) gemm4p<2048,512,RES>:  d_out = x2 + z @ w2 + b2
//
// R4 post-mortem: 23% MfmaUtil matches 19.4cy/MFMA-per-pipe model; per-K-tile
// 4873cy vs 1241cy matrix work -> schedule exposes LDS+latency. R5: faithful
// 4-phase/K-tile template (T3+T4): BK=64 as 2 k-slabs, phase={ds_read subtile,
// stage 1 half, barrier, lgkm0, 16 MFMA (setprio, T5), vmcnt(8) at slab
// boundaries only}. Rotation LDS layout (conflict-free per 8-lane group, T2,
// rule-#21-legal: pre-rotated global source + rotated read, linear LDS dest).
// Coalesced epilogues via LDS bounce (write amp 742 vs 411 MB in R4).

typedef __bf16 bf16x8 __attribute__((ext_vector_type(8)));
typedef float f32x4 __attribute__((ext_vector_type(4)));

constexpr int CDIM = 512;
constexpr int HID = 2048;
constexpr int MROWS = 32 * 3136;  // 100352 = 392 * 256
constexpr float LN_EPS = 1e-5f;

static __device__ __forceinline__ float gelu_tanh(float x) {
  const float u = 0.7978845608028654f * fmaf(0.044715f * x * x, x, x);
  const float e = __expf(2.0f * u);
  return 0.5f * x * (2.0f - 2.0f / (e + 1.0f));
}

static __device__ __forceinline__ void load_lds16(const void* g, void* l) {
  // 16B/lane; LDS dest = wave-uniform base + lane*16 (linear)
  __builtin_amdgcn_global_load_lds((__attribute__((address_space(1))) void*)g,
                                   (__attribute__((address_space(3))) void*)l,
                                   16, 0, 0);
}

// ---------------- weight transpose + bf16 convert ----------------
template <int KD>
__global__ __launch_bounds__(256) void cvt_t(const float* __restrict__ src,
                                             __hip_bfloat16* __restrict__ dst,
                                             int ND) {
  const int i = blockIdx.x * 256 + threadIdx.x;
  const int n = i / KD;
  const int k = i - n * KD;
  dst[i] = __float2bfloat16(src[(size_t)k * ND + n]);
}

// ---------------- fused LN1 + spatial mix + residual + LN2 ----------------
// float2-vectorized: thread handles cols 2t, 2t+1 (same head).
__global__ __launch_bounds__(256) void fused_pre(
    const float* __restrict__ x, const float* __restrict__ g1,
    const float* __restrict__ b1, const float* __restrict__ wsp,
    const float* __restrict__ g2, const float* __restrict__ b2,
    float* __restrict__ x2out, __hip_bfloat16* __restrict__ yout) {
  __shared__ float lnbuf[CDIM];
  __shared__ float red[8];

  const int t = threadIdx.x;
  const int lane = t & 63;
  const int w = t >> 6;
  const int c0 = 2 * t;               // cols c0, c0+1
  const int hd = c0 >> 5, e0 = c0 & 31;

  float wc0[32], wc1[32];
#pragma unroll
  for (int d = 0; d < 32; ++d) {
    const float2 wv = *(const float2*)&wsp[(hd * 32 + d) * 32 + e0];
    wc0[d] = wv.x;
    wc1[d] = wv.y;
  }
  const float2 g1v = *(const float2*)&g1[c0];
  const float2 b1v = *(const float2*)&b1[c0];
  const float2 g2v = *(const float2*)&g2[c0];
  const float2 b2v = *(const float2*)&b2[c0];

  for (int r = blockIdx.x; r < MROWS; r += gridDim.x) {
    const float2 xv = *(const float2*)&x[(size_t)r * CDIM + c0];

    float s = xv.x + xv.y, ss = xv.x * xv.x + xv.y * xv.y;
#pragma unroll
    for (int off = 32; off; off >>= 1) {
      s += __shfl_down(s, off);
      ss += __shfl_down(ss, off);
    }
    if (lane == 0) { red[w * 2] = s; red[w * 2 + 1] = ss; }
    __syncthreads();
    s = red[0] + red[2] + red[4] + red[6];
    ss = red[1] + red[3] + red[5] + red[7];
    float mu = s * (1.0f / CDIM);
    float var = ss * (1.0f / CDIM) - mu * mu;
    float rs = rsqrtf(var + LN_EPS);
    lnbuf[c0] = (xv.x - mu) * rs * g1v.x + b1v.x;
    lnbuf[c0 + 1] = (xv.y - mu) * rs * g1v.y + b1v.y;
    __syncthreads();

    float h0 = 0.f, h1 = 0.f;
#pragma unroll
    for (int d = 0; d < 32; ++d) {
      const float lv = lnbuf[hd * 32 + d];
      h0 = fmaf(lv, wc0[d], h0);
      h1 = fmaf(lv, wc1[d], h1);
    }
    const float a0 = xv.x + h0, a1 = xv.y + h1;
    float2 av;
    av.x = a0;
    av.y = a1;
    *(float2*)&x2out[(size_t)r * CDIM + c0] = av;

    s = a0 + a1;
    ss = a0 * a0 + a1 * a1;
#pragma unroll
    for (int off = 32; off; off >>= 1) {
      s += __shfl_down(s, off);
      ss += __shfl_down(ss, off);
    }
    if (lane == 0) { red[w * 2] = s; red[w * 2 + 1] = ss; }
    __syncthreads();
    s = red[0] + red[2] + red[4] + red[6];
    ss = red[1] + red[3] + red[5] + red[7];
    mu = s * (1.0f / CDIM);
    var = ss * (1.0f / CDIM) - mu * mu;
    rs = rsqrtf(var + LN_EPS);
    __hip_bfloat162 yv;
    yv.x = __float2bfloat16((a0 - mu) * rs * g2v.x + b2v.x);
    yv.y = __float2bfloat16((a1 - mu) * rs * g2v.y + b2v.y);
    *(__hip_bfloat162*)&yout[(size_t)r * CDIM + c0] = yv;
    __syncthreads();
  }
}

// ------- 8-wave 256x256 MFMA GEMM, 4-phase/K-tile counted-vmcnt pipeline ----
// C(MxN) = A(MxK) * Bt(NxK)^T.  BK=64 = 2 slabs x 32k.
// LDS: sm[dbuf2][A/B][slab2][256x32 bf16] = 128 KiB.
// Rotation layout: slab row r, phys 16B-seg q holds logical k-seg
// (q - r - ((r>>2)&1)) & 3  -> fragment ds_read_b128 conflict-free.
// Schedule per K-tile t (dbuf d=t&1): 4 phases (slab, m-half):
//   P1(s0,m0): read af+bfv, stage A-slab1(t+1)->d^1 | P2(s0,m1): af, stage B1(t+1)
//   [vmcnt(8)] P3(s1,m0): af+bfv, stage A-slab0(t+2)->d | P4(s1,m1): af, stage B0(t+2)
//   [vmcnt(8)]  -- never 0 in steady state; 12 loads max in flight.
template <int K, int N, bool GELU>
__global__ __launch_bounds__(512, 2) void gemm4p(
    const __hip_bfloat16* __restrict__ A, const __hip_bfloat16* __restrict__ Bt,
    const float* __restrict__ bias, __hip_bfloat16* __restrict__ zout,
    float* __restrict__ fout) {
  constexpr int NT = N / 256;
  constexpr int NKT = K / 64;  // 8 (gemm1), 32 (gemm2)
  __shared__ __attribute__((aligned(16))) __hip_bfloat16 sm[2][2][2][8192];

  const int tid = threadIdx.x;
  const int lane = tid & 63;
  const int w = tid >> 6;             // 0..7
  const int wm = w >> 2, wn = w & 3;  // wave tile 128x64

  // T1: XCD-aware bijective swizzle (grid % 8 == 0 by construction)
  const int cpx = gridDim.x >> 3;
  const int bid = (blockIdx.x & 7) * cpx + (blockIdx.x >> 3);
  const int tm = bid / NT, tn = bid - tm * NT;
  const size_t am0 = (size_t)tm * 256;
  const int bn0 = tn * 256;

  // staging geometry: thread stages segs tid (rows 0..127) and tid+512 (+128)
  const int srow = tid >> 2;
  const int kphys = tid & 3;
  const int sks = (kphys - srow - ((srow >> 2) & 1)) & 3;  // logical k-seg
  const __hip_bfloat16* pA0 = A + (am0 + srow) * K + sks * 8;
  const __hip_bfloat16* pA1 = pA0 + (size_t)128 * K;
  const __hip_bfloat16* pB0 = Bt + (size_t)(bn0 + srow) * K + sks * 8;
  const __hip_bfloat16* pB1 = pB0 + (size_t)128 * K;
  const int off0 = w * 512;  // elems; wave-uniform LDS base
  const int off1 = 4096 + w * 512;

  // fragment-read geometry (lane-static rotation)
  const int fr = lane & 15, kg = lane >> 4;
  const int kls = (kg + fr + ((fr >> 2) & 1)) & 3;
  const int rbyte = fr * 64 + kls * 16;

  f32x4 acc[8][4] = {};
  bf16x8 af[4], bfv[4];

#define STAGE_A(d, s, t)                                       \
  do {                                                         \
    load_lds16(pA0 + (t) * 64 + (s) * 32, &sm[d][0][s][off0]); \
    load_lds16(pA1 + (t) * 64 + (s) * 32, &sm[d][0][s][off1]); \
  } while (0)
#define STAGE_B(d, s, t)                                       \
  do {                                                         \
    load_lds16(pB0 + (t) * 64 + (s) * 32, &sm[d][1][s][off0]); \
    load_lds16(pB1 + (t) * 64 + (s) * 32, &sm[d][1][s][off1]); \
  } while (0)
#define LOAD_AF(d, s, mh)                                                    \
  do {                                                                       \
    _Pragma("unroll") for (int m = 0; m < 4; ++m) af[m] =                    \
        *(const bf16x8*)((const char*)&sm[d][0][s][0] +                      \
                         (wm * 128 + (mh)*64 + m * 16) * 64 + rbyte);        \
  } while (0)
#define LOAD_BF(d, s)                                                        \
  do {                                                                       \
    _Pragma("unroll") for (int n = 0; n < 4; ++n) bfv[n] =                   \
        *(const bf16x8*)((const char*)&sm[d][1][s][0] + (wn * 64 + n * 16) * \
                             64 + rbyte);                                    \
  } while (0)
#define BAR_LG()                                          \
  do {                                                    \
    __builtin_amdgcn_s_barrier();                         \
    asm volatile("s_waitcnt lgkmcnt(0)" ::: "memory");    \
    __builtin_amdgcn_sched_barrier(0);                    \
  } while (0)
#define MM(mh)                                                            \
  do {                                                                    \
    __builtin_amdgcn_s_setprio(1);                                        \
    _Pragma("unroll") for (int m = 0; m < 4; ++m)                         \
        _Pragma("unroll") for (int n = 0; n < 4; ++n) acc[(mh)*4 + m][n] =\
            __builtin_amdgcn_mfma_f32_16x16x32_bf16(af[m], bfv[n],        \
                                                    acc[(mh)*4 + m][n],   \
                                                    0, 0, 0);             \
    __builtin_amdgcn_s_setprio(0);                                        \
  } while (0)

  // prologue: A0(0) B0(0) A1(0) B1(0) A0(1) B0(1) = 12 loads
  STAGE_A(0, 0, 0);
  STAGE_B(0, 0, 0);
  STAGE_A(0, 1, 0);
  STAGE_B(0, 1, 0);
  STAGE_A(1, 0, 1);
  STAGE_B(1, 0, 1);
  asm volatile("s_waitcnt vmcnt(8)" ::: "memory");  // A0(0),B0(0) resident
  __builtin_amdgcn_s_barrier();

  for (int t = 0; t < NKT; ++t) {
    const int d = t & 1, dn = d ^ 1;
    const bool st1 = (t + 1) < NKT, st2 = (t + 2) < NKT;
    // P1: slab0, m-half0
    LOAD_AF(d, 0, 0);
    LOAD_BF(d, 0);
    if (st1) STAGE_A(dn, 1, t + 1);
    BAR_LG();
    MM(0);
    __builtin_amdgcn_s_barrier();
    // P2: slab0, m-half1
    LOAD_AF(d, 0, 1);
    if (st1) STAGE_B(dn, 1, t + 1);
    BAR_LG();
    MM(1);
    if (st1)
      asm volatile("s_waitcnt vmcnt(8)" ::: "memory");  // A1(t),B1(t) resident
    else
      asm volatile("s_waitcnt vmcnt(0)" ::: "memory");
    __builtin_amdgcn_s_barrier();
    // P3: slab1, m-half0
    LOAD_AF(d, 1, 0);
    LOAD_BF(d, 1);
    if (st2) STAGE_A(d, 0, t + 2);
    BAR_LG();
    MM(0);
    __builtin_amdgcn_s_barrier();
    // P4: slab1, m-half1
    LOAD_AF(d, 1, 1);
    if (st2) STAGE_B(d, 0, t + 2);
    BAR_LG();
    MM(1);
    if (st2)
      asm volatile("s_waitcnt vmcnt(8)" ::: "memory");  // A0/B0(t+1) resident
    else if (st1)
      asm volatile("s_waitcnt vmcnt(4)" ::: "memory");
    __builtin_amdgcn_s_barrier();
  }
#undef STAGE_A
#undef STAGE_B
#undef LOAD_AF
#undef LOAD_BF
#undef BAR_LG
#undef MM

  // ---- epilogue via LDS bounce: coalesced global writes ----
  // C/D map: col = lane&15, row = (lane>>4)*4 + j  [m89/m91-verified]
  const int cr = (lane >> 4) * 4;
  const int cc = lane & 15;
  char* smb = (char*)&sm[0][0][0][0];

  if constexpr (GELU) {
    // bf16 out: full 256x256 tile = 128KB in LDS, then coalesced stores
    __hip_bfloat16* ot = (__hip_bfloat16*)smb;
#pragma unroll
    for (int n = 0; n < 4; ++n) {
      const int col = wn * 64 + n * 16 + cc;
      const float bv = bias[bn0 + col];
#pragma unroll
      for (int m = 0; m < 8; ++m) {
        const int row = wm * 128 + m * 16 + cr;
#pragma unroll
        for (int j = 0; j < 4; ++j)
          ot[(row + j) * 256 + col] = __float2bfloat16(gelu_tanh(acc[m][n][j] + bv));
      }
    }
    __syncthreads();
#pragma unroll
    for (int it = 0; it < 16; ++it) {
      const int seg = it * 512 + tid;
      const int row = seg >> 5, ch = seg & 31;
      const uint4 v = *(const uint4*)(smb + seg * 16);
      *(uint4*)&zout[(am0 + row) * N + bn0 + ch * 8] = v;
    }
  } else {
    // fp32 RMW out: two passes of 128 rows (128x256 f32 = 128KB)
#pragma unroll
    for (int p = 0; p < 2; ++p) {
      if (p) __syncthreads();  // protect LDS reuse between passes
      if (wm == p) {
        float* ot = (float*)smb;
#pragma unroll
        for (int n = 0; n < 4; ++n) {
          const int col = wn * 64 + n * 16 + cc;
          const float bv = bias[bn0 + col];
#pragma unroll
          for (int m = 0; m < 8; ++m) {
            const int row = m * 16 + cr;
#pragma unroll
            for (int j = 0; j < 4; ++j)
              ot[(row + j) * 256 + col] = acc[m][n][j] + bv;
          }
        }
      }
      __syncthreads();
#pragma unroll
      for (int it = 0; it < 16; ++it) {
        const int seg = it * 512 + tid;
        const int row = seg >> 6, ch = seg & 63;
        const float4 lv = *(const float4*)(smb + seg * 16);
        float* gp = &fout[(am0 + p * 128 + row) * N + bn0 + ch * 4];
        float4 o = *(const float4*)gp;
        o.x += lv.x;
        o.y += lv.y;
        o.z += lv.z;
        o.w += lv.w;
        *(float4*)gp = o;
      }
    }
  }
}

extern "C" void kernel_launch(void* const* d_in, const int* in_sizes, int n_in,
                              void* d_out, int out_size, void* d_ws,
                              size_t ws_size, hipStream_t stream) {
  const float* x = (const float*)d_in[0];
  const float* n1g = (const float*)d_in[1];
  const float* n1b = (const float*)d_in[2];
  const float* wsp = (const float*)d_in[3];
  const float* n2g = (const float*)d_in[4];
  const float* n2b = (const float*)d_in[5];
  const float* w1 = (const float*)d_in[6];
  const float* b1 = (const float*)d_in[7];
  const float* w2 = (const float*)d_in[8];
  const float* b2 = (const float*)d_in[9];
  float* out = (float*)d_out;

  // ws layout (bf16): y[M*512] | z[M*2048] | w1t[2048*512] | w2t[512*2048]
  __hip_bfloat16* ybuf = (__hip_bfloat16*)d_ws;
  __hip_bfloat16* zbuf = ybuf + (size_t)MROWS * CDIM;
  __hip_bfloat16* w1t = zbuf + (size_t)MROWS * HID;
  __hip_bfloat16* w2t = w1t + (size_t)CDIM * HID;

  cvt_t<CDIM><<<(CDIM * HID) / 256, 256, 0, stream>>>(w1, w1t, HID);
  cvt_t<HID><<<(CDIM * HID) / 256, 256, 0, stream>>>(w2, w2t, CDIM);
  fused_pre<<<2048, 256, 0, stream>>>(x, n1g, n1b, wsp, n2g, n2b, out, ybuf);
  // grids: 392*8 = 3136 and 392*2 = 784, both % 8 == 0
  gemm4p<CDIM, HID, true><<<(MROWS / 256) * (HID / 256), 512, 0, stream>>>(
      ybuf, w1t, b1, zbuf, nullptr);
  gemm4p<HID, CDIM, false><<<(MROWS / 256) * (CDIM / 256), 512, 0, stream>>>(
      zbuf, w2t, b2, nullptr, out);
}

// Round 7
// 938.035 us; speedup vs baseline: 1.0244x; 1.0244x over previous
//
#include <hip/hip_runtime.h>
#include <hip/hip_bf16.h>

// SwinMLP block, fp32 in/out, bf16 MFMA internals.
//   1) cvt_t: w1 -> w1t (bf16, NxK), w2 -> w2t (bf16, NxK)  [LDS tile transpose]
//   2) fused_pre: LN1 + per-head 32x32 spatial mix + residual -> x2 (d_out)
//      + LN2(x2) -> y (bf16, ws)
//   3) gemm8p<512,2048,GELU>: z = gelu(y @ w1 + b1)  (bf16, ws)
//   4) gemm8p<2048,512,RES>:  d_out = x2 + z @ w2 + b2
//
// R4: 8-wave 256², 4-slot ring, distance-2 counted vmcnt -> 399us/gemm (PASSED)
// R5: 4-phase + lgkm fences -> regressed (m141 anti-pattern)
// R6: 2-slot ring -> RACE (stage into slot other waves still read). Reverted.
// R7 (this): R4 K-loop VERBATIM (proven ledger: slot (t+2)&3 last read at
//   t-2, sealed by top-of-(t-1) barrier) + verified-mechanism fixes only:
//   - LDS-bounce epilogues (write-amp: gemm1 742->~430MB, gemm2 737->~220MB)
//   - coalesced cvt_t via 64x64 LDS tile transpose
//   - float2 fused_pre (R5-passed)

typedef __bf16 bf16x8 __attribute__((ext_vector_type(8)));
typedef float f32x4 __attribute__((ext_vector_type(4)));

constexpr int CDIM = 512;
constexpr int HID = 2048;
constexpr int MROWS = 32 * 3136;  // 100352 = 392 * 256
constexpr float LN_EPS = 1e-5f;

static __device__ __forceinline__ float gelu_tanh(float x) {
  const float u = 0.7978845608028654f * fmaf(0.044715f * x * x, x, x);
  const float e = __expf(2.0f * u);
  return 0.5f * x * (2.0f - 2.0f / (e + 1.0f));
}

static __device__ __forceinline__ void load_lds16(const void* g, void* l) {
  // 16B/lane; LDS dest = wave-uniform base + lane*16 (linear)
  __builtin_amdgcn_global_load_lds((__attribute__((address_space(1))) void*)g,
                                   (__attribute__((address_space(3))) void*)l,
                                   16, 0, 0);
}

// ---- transpose fp32 src[KD][ND] -> bf16 dst[ND][KD], 64x64 LDS tiles ----
// Coalesced float4 loads, coalesced 8B bf16x4 stores; LDS 2-way (free).
template <int KD, int ND>
__global__ __launch_bounds__(256) void cvt_t(const float* __restrict__ src,
                                             __hip_bfloat16* __restrict__ dst) {
  __shared__ float tl[64][65];
  const int t = threadIdx.x;
  constexpr int NTN = ND / 64;
  const int k0 = (blockIdx.x / NTN) * 64;
  const int n0 = (blockIdx.x % NTN) * 64;
  const int c4 = (t & 15) * 4;
  const int r = t >> 4;  // 0..15
#pragma unroll
  for (int j = 0; j < 4; ++j) {
    const int kk = r + j * 16;
    const float4 v = *(const float4*)&src[(size_t)(k0 + kk) * ND + n0 + c4];
    tl[c4 + 0][kk] = v.x;
    tl[c4 + 1][kk] = v.y;
    tl[c4 + 2][kk] = v.z;
    tl[c4 + 3][kk] = v.w;
  }
  __syncthreads();
#pragma unroll
  for (int j = 0; j < 4; ++j) {
    const int nn = r + j * 16;
    __hip_bfloat16 o[4];
#pragma unroll
    for (int c = 0; c < 4; ++c) o[c] = __float2bfloat16(tl[nn][c4 + c]);
    *(uint2*)&dst[(size_t)(n0 + nn) * KD + k0 + c4] = *(const uint2*)o;
  }
}

// ---------------- fused LN1 + spatial mix + residual + LN2 ----------------
__global__ __launch_bounds__(256) void fused_pre(
    const float* __restrict__ x, const float* __restrict__ g1,
    const float* __restrict__ b1, const float* __restrict__ wsp,
    const float* __restrict__ g2, const float* __restrict__ b2,
    float* __restrict__ x2out, __hip_bfloat16* __restrict__ yout) {
  __shared__ float lnbuf[CDIM];
  __shared__ float red[8];

  const int t = threadIdx.x;
  const int lane = t & 63;
  const int w = t >> 6;
  const int c0 = 2 * t;  // cols c0, c0+1 (same head)
  const int hd = c0 >> 5, e0 = c0 & 31;

  float wc0[32], wc1[32];
#pragma unroll
  for (int d = 0; d < 32; ++d) {
    const float2 wv = *(const float2*)&wsp[(hd * 32 + d) * 32 + e0];
    wc0[d] = wv.x;
    wc1[d] = wv.y;
  }
  const float2 g1v = *(const float2*)&g1[c0];
  const float2 b1v = *(const float2*)&b1[c0];
  const float2 g2v = *(const float2*)&g2[c0];
  const float2 b2v = *(const float2*)&b2[c0];

  for (int r = blockIdx.x; r < MROWS; r += gridDim.x) {
    const float2 xv = *(const float2*)&x[(size_t)r * CDIM + c0];

    float s = xv.x + xv.y, ss = xv.x * xv.x + xv.y * xv.y;
#pragma unroll
    for (int off = 32; off; off >>= 1) {
      s += __shfl_down(s, off);
      ss += __shfl_down(ss, off);
    }
    if (lane == 0) { red[w * 2] = s; red[w * 2 + 1] = ss; }
    __syncthreads();
    s = red[0] + red[2] + red[4] + red[6];
    ss = red[1] + red[3] + red[5] + red[7];
    float mu = s * (1.0f / CDIM);
    float var = ss * (1.0f / CDIM) - mu * mu;
    float rs = rsqrtf(var + LN_EPS);
    lnbuf[c0] = (xv.x - mu) * rs * g1v.x + b1v.x;
    lnbuf[c0 + 1] = (xv.y - mu) * rs * g1v.y + b1v.y;
    __syncthreads();

    float h0 = 0.f, h1 = 0.f;
#pragma unroll
    for (int d = 0; d < 32; ++d) {
      const float lv = lnbuf[hd * 32 + d];
      h0 = fmaf(lv, wc0[d], h0);
      h1 = fmaf(lv, wc1[d], h1);
    }
    const float a0 = xv.x + h0, a1 = xv.y + h1;
    float2 av;
    av.x = a0;
    av.y = a1;
    *(float2*)&x2out[(size_t)r * CDIM + c0] = av;

    s = a0 + a1;
    ss = a0 * a0 + a1 * a1;
#pragma unroll
    for (int off = 32; off; off >>= 1) {
      s += __shfl_down(s, off);
      ss += __shfl_down(ss, off);
    }
    if (lane == 0) { red[w * 2] = s; red[w * 2 + 1] = ss; }
    __syncthreads();
    s = red[0] + red[2] + red[4] + red[6];
    ss = red[1] + red[3] + red[5] + red[7];
    mu = s * (1.0f / CDIM);
    var = ss * (1.0f / CDIM) - mu * mu;
    rs = rsqrtf(var + LN_EPS);
    __hip_bfloat162 yv;
    yv.x = __float2bfloat16((a0 - mu) * rs * g2v.x + b2v.x);
    yv.y = __float2bfloat16((a1 - mu) * rs * g2v.y + b2v.y);
    *(__hip_bfloat162*)&yout[(size_t)r * CDIM + c0] = yv;
    __syncthreads();
  }
}

// ------- 8-wave 256x256 MFMA GEMM, counted-vmcnt ring pipeline (R4) -------
// C(MxN) = A(MxK) * Bt(NxK)^T.  BK=32; LDS = 4 slots x {A 16KB, B 16KB}.
// Prefetch distance 2; top-of-tile vmcnt(4) certifies tile t; slot (t+2)&3
// was last read at t-2, sealed by the top-of-(t-1) barrier (race-free).
template <int K, int N, bool GELU>
__global__ __launch_bounds__(512, 2) void gemm8p(
    const __hip_bfloat16* __restrict__ A, const __hip_bfloat16* __restrict__ Bt,
    const float* __restrict__ bias, __hip_bfloat16* __restrict__ zout,
    float* __restrict__ fout) {
  constexpr int NT = N / 256;
  constexpr int NKT = K / 32;
  __shared__ __attribute__((aligned(16))) __hip_bfloat16 lds[4][2][256 * 32];

  const int tid = threadIdx.x;
  const int lane = tid & 63;
  const int w = tid >> 6;             // 0..7
  const int wm = w >> 2, wn = w & 3;  // wave tile 128x64 (2M x 4N)

  // T1: XCD-aware bijective swizzle (grid % 8 == 0 by construction)
  const int cpx = gridDim.x >> 3;
  const int bid = (blockIdx.x & 7) * cpx + (blockIdx.x >> 3);
  const int tm = bid / NT, tn = bid - tm * NT;
  const size_t am0 = (size_t)tm * 256;
  const int bn0 = tn * 256;

  // staging: thread stages segs tid (rows 0..127) and tid+512 (rows 128..255)
  const int r0 = tid >> 2;
  const int ks0 = (tid & 3) ^ ((tid >> 2) & 3) ^ ((tid >> 4) & 3);
  const __hip_bfloat16* aP0 = A + (am0 + r0) * K + ks0 * 8;
  const __hip_bfloat16* aP1 = aP0 + (size_t)128 * K;
  const __hip_bfloat16* bP0 = Bt + (size_t)(bn0 + r0) * K + ks0 * 8;
  const __hip_bfloat16* bP1 = bP0 + (size_t)128 * K;
  const int lo0 = (w * 64) * 8;
  const int lo1 = (512 + w * 64) * 8;

#define STAGE_A(sl, kt)                            \
  do {                                             \
    load_lds16(aP0 + (kt) * 32, &lds[sl][0][lo0]); \
    load_lds16(aP1 + (kt) * 32, &lds[sl][0][lo1]); \
  } while (0)
#define STAGE_B(sl, kt)                            \
  do {                                             \
    load_lds16(bP0 + (kt) * 32, &lds[sl][1][lo0]); \
    load_lds16(bP1 + (kt) * 32, &lds[sl][1][lo1]); \
  } while (0)

  f32x4 acc[8][4] = {};
  const int fr = lane & 15;
  const int kgs = (((lane >> 4) ^ (lane & 3) ^ ((lane >> 2) & 3))) * 8;

  // prologue: tiles 0,1 -> slots 0,1 (8 loads in flight)
  STAGE_A(0, 0);
  STAGE_B(0, 0);
  STAGE_A(1, 1);
  STAGE_B(1, 1);

  for (int t = 0; t < NKT; ++t) {
    if (t + 1 < NKT)
      asm volatile("s_waitcnt vmcnt(4)" ::: "memory");
    else
      asm volatile("s_waitcnt vmcnt(0)" ::: "memory");
    __builtin_amdgcn_s_barrier();

    const int sl = t & 3;
    const int s2 = (t + 2) & 3;
    const bool pf = (t + 2) < NKT;
    const __hip_bfloat16* As = lds[sl][0];
    const __hip_bfloat16* Bs = lds[sl][1];

    // ---- phase 0: issue A-stage(t+2); compute m=0..3 x all n ----
    if (pf) STAGE_A(s2, t + 2);
    bf16x8 bfv[4];
#pragma unroll
    for (int n = 0; n < 4; ++n)
      bfv[n] = *(const bf16x8*)(Bs + (wn * 64 + n * 16 + fr) * 32 + kgs);
    bf16x8 af[4];
#pragma unroll
    for (int m = 0; m < 4; ++m)
      af[m] = *(const bf16x8*)(As + (wm * 128 + m * 16 + fr) * 32 + kgs);
    __builtin_amdgcn_s_setprio(1);
#pragma unroll
    for (int m = 0; m < 4; ++m)
#pragma unroll
      for (int n = 0; n < 4; ++n)
        acc[m][n] = __builtin_amdgcn_mfma_f32_16x16x32_bf16(af[m], bfv[n],
                                                            acc[m][n], 0, 0, 0);
    __builtin_amdgcn_s_setprio(0);
    __builtin_amdgcn_s_barrier();

    // ---- phase 1: issue B-stage(t+2); compute m=4..7 (reuse bfv) ----
    if (pf) STAGE_B(s2, t + 2);
#pragma unroll
    for (int m = 0; m < 4; ++m)
      af[m] = *(const bf16x8*)(As + (wm * 128 + (m + 4) * 16 + fr) * 32 + kgs);
    __builtin_amdgcn_s_setprio(1);
#pragma unroll
    for (int m = 0; m < 4; ++m)
#pragma unroll
      for (int n = 0; n < 4; ++n)
        acc[m + 4][n] = __builtin_amdgcn_mfma_f32_16x16x32_bf16(
            af[m], bfv[n], acc[m + 4][n], 0, 0, 0);
    __builtin_amdgcn_s_setprio(0);
  }
#undef STAGE_A
#undef STAGE_B

  // ---- epilogue via LDS bounce: full-line coalesced global writes ----
  // C/D map: col = lane&15, row = (lane>>4)*4 + j  [m89/m91-verified]
  const int cr = (lane >> 4) * 4;
  const int cc = lane & 15;
  char* smb = (char*)&lds[0][0][0];

  if constexpr (GELU) {
    // bf16 out: full 256x256 tile = 128KB in LDS
    __syncthreads();  // all waves past final phase-1 ds_reads
    __hip_bfloat16* ot = (__hip_bfloat16*)smb;
#pragma unroll
    for (int n = 0; n < 4; ++n) {
      const int col = wn * 64 + n * 16 + cc;
      const float bv = bias[bn0 + col];
#pragma unroll
      for (int m = 0; m < 8; ++m) {
        const int row = wm * 128 + m * 16 + cr;
#pragma unroll
        for (int j = 0; j < 4; ++j)
          ot[(row + j) * 256 + col] =
              __float2bfloat16(gelu_tanh(acc[m][n][j] + bv));
      }
    }
    __syncthreads();
#pragma unroll
    for (int it = 0; it < 16; ++it) {
      const int seg = it * 512 + tid;  // 8192 x 16B = 128KB
      const int row = seg >> 5, cs = seg & 31;
      const uint4 v = *(const uint4*)(smb + seg * 16);
      *(uint4*)&zout[(am0 + row) * N + bn0 + cs * 8] = v;
    }
  } else {
    // fp32 RMW out: 2 passes of 128 rows ([128][256] f32 = 128KB)
    float* ot = (float*)smb;
#pragma unroll
    for (int p = 0; p < 2; ++p) {
      __syncthreads();  // pass-p LDS region free (and K-loop reads done, p=0)
      if (wm == p) {
#pragma unroll
        for (int n = 0; n < 4; ++n) {
          const int col = wn * 64 + n * 16 + cc;
          const float bv = bias[bn0 + col];
#pragma unroll
          for (int m = 0; m < 8; ++m) {
            const int rl = m * 16 + cr;
#pragma unroll
            for (int j = 0; j < 4; ++j)
              ot[(rl + j) * 256 + col] = acc[m][n][j] + bv;
          }
        }
      }
      __syncthreads();
#pragma unroll
      for (int it = 0; it < 16; ++it) {
        const int seg = it * 512 + tid;  // 8192 x 16B = 128KB
        const int row = seg >> 6, cs = seg & 63;
        const float4 lv = *(const float4*)(smb + seg * 16);
        float* gp = &fout[(am0 + p * 128 + row) * N + bn0 + cs * 4];
        float4 o = *(const float4*)gp;
        o.x += lv.x;
        o.y += lv.y;
        o.z += lv.z;
        o.w += lv.w;
        *(float4*)gp = o;
      }
    }
  }
}

extern "C" void kernel_launch(void* const* d_in, const int* in_sizes, int n_in,
                              void* d_out, int out_size, void* d_ws,
                              size_t ws_size, hipStream_t stream) {
  const float* x = (const float*)d_in[0];
  const float* n1g = (const float*)d_in[1];
  const float* n1b = (const float*)d_in[2];
  const float* wsp = (const float*)d_in[3];
  const float* n2g = (const float*)d_in[4];
  const float* n2b = (const float*)d_in[5];
  const float* w1 = (const float*)d_in[6];
  const float* b1 = (const float*)d_in[7];
  const float* w2 = (const float*)d_in[8];
  const float* b2 = (const float*)d_in[9];
  float* out = (float*)d_out;

  // ws layout (bf16): y[M*512] | z[M*2048] | w1t[2048*512] | w2t[512*2048]
  __hip_bfloat16* ybuf = (__hip_bfloat16*)d_ws;
  __hip_bfloat16* zbuf = ybuf + (size_t)MROWS * CDIM;
  __hip_bfloat16* w1t = zbuf + (size_t)MROWS * HID;
  __hip_bfloat16* w2t = w1t + (size_t)CDIM * HID;

  cvt_t<CDIM, HID><<<(CDIM / 64) * (HID / 64), 256, 0, stream>>>(w1, w1t);
  cvt_t<HID, CDIM><<<(HID / 64) * (CDIM / 64), 256, 0, stream>>>(w2, w2t);
  fused_pre<<<2048, 256, 0, stream>>>(x, n1g, n1b, wsp, n2g, n2b, out, ybuf);
  // grids: 392*8 = 3136 and 392*2 = 784, both % 8 == 0
  gemm8p<CDIM, HID, true><<<(MROWS / 256) * (HID / 256), 512, 0, stream>>>(
      ybuf, w1t, b1, zbuf, nullptr);
  gemm8p<HID, CDIM, false><<<(MROWS / 256) * (CDIM / 256), 512, 0, stream>>>(
      zbuf, w2t, b2, nullptr, out);
}